// Round 2
// 155.107 us; speedup vs baseline: 1.0098x; 1.0098x over previous
//
#include <hip/hip_runtime.h>
#include <math.h>

#define HH 128
#define WW 128
#define CC 64
#define BB 8
#define OC 64
#define OFFC 18
#define HW (HH*WW)
#define HP 136
#define WP 136
#define PHW (HP*WP)   /* 18496 */

typedef __attribute__((ext_vector_type(8))) _Float16 f16x8;
typedef __attribute__((ext_vector_type(4))) float f32x4;

// ws layout (floats):
//   P16:    8 img * 8 groups * PHW uint4 (8 fp16 ch each) = BB*32*PHW floats
//   offs:   8*18*128*128 = 2359296 (fp32)
//   wA_reg: 36864 fp16 (18432 fl) A-frag [(tap*2+kk)*64+o][quad][8j]
//   wA_off: 18432 fp16 (9216 fl)  [(tap*2+kk)*32+o][quad][8j], rows 18..31 zero
#define P_OFF      0
#define P_SIZE     (BB*32*PHW)
#define OFFS_OFF   (P_OFF + P_SIZE)
#define OFFS_SIZE  (BB*OFFC*HW)
#define WAREG_OFF  (OFFS_OFF + OFFS_SIZE)
#define WAREG_SIZE 18432
#define WAOFF_OFF  (WAREG_OFF + WAREG_SIZE)

__device__ __forceinline__ unsigned short f2h(float f) {
    _Float16 t = (_Float16)f;
    unsigned short s;
    __builtin_memcpy(&s, &t, 2);
    return s;
}
__device__ __forceinline__ f16x8 u4_to_h8(uint4 u) {
    union { uint4 u; f16x8 h; } c; c.u = u; return c.h;
}
__device__ __forceinline__ uint4 h8_to_u4(f16x8 h) {
    union { uint4 u; f16x8 h; } c; c.h = h; return c.u;
}
__device__ __forceinline__ f16x8 splat8(float f) {
    _Float16 t = (_Float16)f;
    return (f16x8){t, t, t, t, t, t, t, t};
}

__global__ __launch_bounds__(256) void prep_kernel(
    const float* __restrict__ w_reg, const float* __restrict__ w_off,
    unsigned short* __restrict__ wA_reg, unsigned short* __restrict__ wA_off)
{
    int i = blockIdx.x * 256 + threadIdx.x;
    if (i < 18 * 64 * 32) {
        int j = i & 7, quad = (i >> 3) & 3, o = (i >> 5) & 63, ks = i >> 11;
        int kt = ks >> 1, kk = ks & 1;
        int c = kk * 32 + quad * 8 + j;
        wA_reg[i] = f2h(w_reg[o * 576 + c * 9 + kt]);
    }
    if (i < 18 * 32 * 32) {
        int j = i & 7, quad = (i >> 3) & 3, o = (i >> 5) & 31, ks = i >> 10;
        int kt = ks >> 1, kk = ks & 1;
        int c = kk * 32 + quad * 8 + j;
        float v = (o < OFFC) ? w_off[(o * CC + c) * 9 + kt] : 0.0f;
        wA_off[i] = f2h(v);
    }
}

// Zero-padded fp16 P: uint4 at [(img*8+g)*PHW + r*WP + col] = channels g*8..g*8+7.
__global__ __launch_bounds__(256) void pad_kernel(
    const float* __restrict__ x, uint4* __restrict__ P)
{
    int idx = blockIdx.x * 256 + threadIdx.x;     // over BB*8*PHW = 1183744
    if (idx >= BB * 8 * PHW) return;
    int pos = idx % PHW;
    int ig  = idx / PHW;          // img*8 + g
    int r   = pos / WP;
    int col = pos % WP;
    union { uint4 u; f16x8 h; } cv;
    cv.u = make_uint4(0u, 0u, 0u, 0u);
    if (r >= 4 && r <= 131 && col >= 4 && col <= 131) {
        const float* src = x + (ig * 8) * HW + (r - 4) * WW + (col - 4);
        #pragma unroll
        for (int e = 0; e < 8; ++e)
            cv.h[e] = (_Float16)src[e * HW];
    }
    P[idx] = cv.u;
}

// Offset conv: stage full 3-row x 130-col x 64-ch fp16 strip (pure uint4 copy),
// one barrier, 72 back-to-back f16 MFMAs on shifted views.
__global__ __launch_bounds__(256) void offset_conv_kernel(
    const uint4* __restrict__ P, const unsigned short* __restrict__ wA_off,
    const float* __restrict__ b_off, float* __restrict__ offs)
{
    __shared__ uint4 xs[3 * 8 * 132];          // [r(3)][g(8)][j(132)] 8ch fp16
    int img  = blockIdx.x & 7;
    int pblk = blockIdx.x >> 3;                // row hv
    int tid  = threadIdx.x;
    const f16x8* wAv = (const f16x8*)wA_off;
    int lane = tid & 63;
    int wvid = tid >> 6;
    int s  = wvid & 1;                         // o-strip
    int ph = wvid >> 1;                        // px half

    for (int i = tid; i < 3 * 8 * 130; i += 256) {
        int r   = i / 1040;
        int rem = i - r * 1040;
        int g   = rem / 130;
        int j   = rem - g * 130;
        xs[(r * 8 + g) * 132 + j] =
            P[(img * 8 + g) * PHW + (pblk + 3 + r) * WP + (j + 3)];
    }
    __syncthreads();

    f32x4 acc[4];
    #pragma unroll
    for (int pt = 0; pt < 4; ++pt) acc[pt] = (f32x4){0.f, 0.f, 0.f, 0.f};

    const f16x8* xsv = (const f16x8*)xs;
    for (int tap = 0; tap < 9; ++tap) {
        int dy = tap / 3, dx = tap % 3;
        f16x8 a0 = wAv[((tap * 2 + 0) * 32 + s * 16 + (lane & 15)) * 4 + (lane >> 4)];
        f16x8 a1 = wAv[((tap * 2 + 1) * 32 + s * 16 + (lane & 15)) * 4 + (lane >> 4)];
        #pragma unroll
        for (int pt = 0; pt < 4; ++pt) {
            int j = ph * 64 + pt * 16 + (lane & 15) + dx;
            f16x8 b0 = xsv[(dy * 8 + (lane >> 4)) * 132 + j];
            acc[pt] = __builtin_amdgcn_mfma_f32_16x16x32_f16(a0, b0, acc[pt], 0, 0, 0);
            f16x8 b1 = xsv[(dy * 8 + 4 + (lane >> 4)) * 132 + j];
            acc[pt] = __builtin_amdgcn_mfma_f32_16x16x32_f16(a1, b1, acc[pt], 0, 0, 0);
        }
    }

    float* ob = offs + img * (OFFC * HW) + pblk * 128;
    #pragma unroll
    for (int r = 0; r < 4; ++r) {
        int o = s * 16 + (lane >> 4) * 4 + r;
        if (o < OFFC) {
            float bias = b_off[o];
            #pragma unroll
            for (int pt = 0; pt < 4; ++pt) {
                int pxl = ph * 64 + pt * 16 + (lane & 15);
                ob[o * HW + pxl] = acc[pt][r] + bias;
            }
        }
    }
}

// ---- deform: software-pipelined version ----
// Per tap t the corner gathers + A-frags were ISSUED in iteration t-1 (offsets
// two taps ahead), so their L2/L3 latency hides under barrier + ds_read + 16
// MFMAs + next blend. Barrier is raw s_barrier with lgkmcnt-only drain so the
// in-flight global loads survive it (T4-style counted-vmcnt idea: never drain
// vmcnt in the loop). Numerics identical to previous verified kernel.

struct Gather8 {
    uint4 a00, a01, a10, a11;   // group qp*2
    uint4 b00, b01, b10, b11;   // group qp*2+1
    float wx1, wy1;
};

__device__ __forceinline__ Gather8 issue_tap(
    const uint4* __restrict__ xq0, const uint4* __restrict__ xq1,
    int wv, int hv, int dx, int dy, float offx, float offy)
{
    const float scale = 129.0f / 127.0f;
    // bit-identical to original: ((float)wv + (float)dx) + offx
    float pxf = ((float)wv + (float)dx) + offx;
    float pyf = ((float)hv + (float)dy) + offy;
    float qx = fminf(fmaxf(pxf * scale, -100.0f), 300.0f);
    float qy = fminf(fmaxf(pyf * scale, -100.0f), 300.0f);
    float x0f = floorf(qx), y0f = floorf(qy);
    Gather8 g;
    g.wx1 = qx - x0f;
    g.wy1 = qy - y0f;
    int ix0 = (int)x0f, iy0 = (int)y0f;
    int c0 = min(max(ix0 + 3, 0), WP - 2);
    int r0 = min(max(iy0 + 3, 0), HP - 1);
    int r1 = min(max(iy0 + 4, 0), HP - 1);
    int pr0 = r0 * WP + c0, pr1 = r1 * WP + c0;
    g.a00 = xq0[pr0]; g.a01 = xq0[pr0 + 1];
    g.a10 = xq0[pr1]; g.a11 = xq0[pr1 + 1];
    g.b00 = xq1[pr0]; g.b01 = xq1[pr0 + 1];
    g.b10 = xq1[pr1]; g.b11 = xq1[pr1 + 1];
    return g;
}

__device__ __forceinline__ void blend_write(
    uint4* __restrict__ dst, int qp, int pxl, const Gather8& g)
{
    f16x8 wx1v = splat8(g.wx1), wx0v = splat8(1.0f - g.wx1);
    f16x8 wy1v = splat8(g.wy1), wy0v = splat8(1.0f - g.wy1);
    f16x8 r0a = u4_to_h8(g.a00) * wx0v + u4_to_h8(g.a01) * wx1v;
    f16x8 r1a = u4_to_h8(g.a10) * wx0v + u4_to_h8(g.a11) * wx1v;
    dst[(qp * 2 + 0) * 64 + pxl] = h8_to_u4(r0a * wy0v + r1a * wy1v);
    f16x8 r0b = u4_to_h8(g.b00) * wx0v + u4_to_h8(g.b01) * wx1v;
    f16x8 r1b = u4_to_h8(g.b10) * wx0v + u4_to_h8(g.b11) * wx1v;
    dst[(qp * 2 + 1) * 64 + pxl] = h8_to_u4(r0b * wy0v + r1b * wy1v);
}

__global__ __launch_bounds__(256, 4) void deform_main_kernel(
    const uint4* __restrict__ P, const float* __restrict__ offs,
    const unsigned short* __restrict__ wA_reg, const float* __restrict__ b_reg,
    float* __restrict__ out)
{
    __shared__ uint4 xs2[2 * 512];             // 16 KB: [buf][g(8)][px(64)]
    int img  = blockIdx.x & 7;
    int rest = blockIdx.x >> 3;                // 0..255
    int half = rest & 1;
    int pblk = rest >> 1;                      // row 0..127
    int tid  = threadIdx.x;
    int pxl  = tid & 63;                       // local px
    int qp   = tid >> 6;                       // group pair 0..3
    int wv = half * 64 + pxl;
    int hv = pblk;
    const float*  obf = offs + img * (OFFC * HW) + hv * WW + wv;
    const f16x8*  wAv = (const f16x8*)wA_reg;
    int lane = tid & 63;
    int wvid = tid >> 6;                       // o-strip = wvid*16
    const uint4* xq0 = P + (img * 8 + qp * 2 + 0) * PHW;
    const uint4* xq1 = P + (img * 8 + qp * 2 + 1) * PHW;
    int aidx = (wvid * 16 + (lane & 15)) * 4 + (lane >> 4);   // A-frag lane slot

    f32x4 acc[4];
    #pragma unroll
    for (int pt = 0; pt < 4; ++pt) acc[pt] = (f32x4){0.f, 0.f, 0.f, 0.f};

    // --- pipeline prologue ---
    float ox0 = obf[0],      oy0 = obf[HW];        // tap 0 offsets
    float ox1 = obf[2 * HW], oy1 = obf[3 * HW];    // tap 1 offsets
    Gather8 cur = issue_tap(xq0, xq1, wv, hv, -1, -1, ox0, oy0);
    f16x8 a0c = wAv[0 * 64 * 4 + aidx];            // tap 0 A-frags
    f16x8 a1c = wAv[1 * 64 * 4 + aidx];

    #pragma unroll
    for (int tap = 0; tap < 9; ++tap) {
        // 1. blend current corners (auto vmcnt wait on use) and write LDS
        uint4* dst = xs2 + (tap & 1) * 512;
        blend_write(dst, qp, pxl, cur);

        // 2. prefetch offsets two taps ahead
        float ox2 = 0.f, oy2 = 0.f;
        if (tap < 7) {
            ox2 = obf[(2 * tap + 4) * HW];
            oy2 = obf[(2 * tap + 5) * HW];
        }

        // 3. issue next tap's gathers + A-frags (stay in flight across barrier)
        Gather8 nxt;
        f16x8 a0n, a1n;
        if (tap < 8) {
            int dx1 = (tap + 1) % 3 - 1, dy1 = (tap + 1) / 3 - 1;
            nxt = issue_tap(xq0, xq1, wv, hv, dx1, dy1, ox1, oy1);
            a0n = wAv[((tap + 1) * 2 + 0) * 64 * 4 + aidx];
            a1n = wAv[((tap + 1) * 2 + 1) * 64 * 4 + aidx];
        }

        // 4. barrier: drain LDS ops only — prefetched global loads survive
        asm volatile("s_waitcnt lgkmcnt(0)" ::: "memory");
        __builtin_amdgcn_s_barrier();
        asm volatile("" ::: "memory");   // keep ds_reads below the barrier

        // 5. consume this tap's LDS tile: 16 MFMAs
        const f16x8* xsv = (const f16x8*)(xs2 + (tap & 1) * 512);
        #pragma unroll
        for (int pt = 0; pt < 4; ++pt) {
            int pxi = pt * 16 + (lane & 15);
            f16x8 b0 = xsv[(lane >> 4) * 64 + pxi];
            acc[pt] = __builtin_amdgcn_mfma_f32_16x16x32_f16(a0c, b0, acc[pt], 0, 0, 0);
            f16x8 b1 = xsv[(4 + (lane >> 4)) * 64 + pxi];
            acc[pt] = __builtin_amdgcn_mfma_f32_16x16x32_f16(a1c, b1, acc[pt], 0, 0, 0);
        }

        // 6. rotate pipeline registers (SSA — loop is fully unrolled)
        if (tap < 8) {
            cur = nxt; a0c = a0n; a1c = a1n;
            ox1 = ox2; oy1 = oy2;
        }
    }

    float* op = out + img * (OC * HW) + hv * WW + half * 64;
    #pragma unroll
    for (int r = 0; r < 4; ++r) {
        int o = wvid * 16 + (lane >> 4) * 4 + r;
        float bias = b_reg[o];
        #pragma unroll
        for (int pt = 0; pt < 4; ++pt)
            op[o * HW + pt * 16 + (lane & 15)] = acc[pt][r] + bias;
    }
}

extern "C" void kernel_launch(void* const* d_in, const int* in_sizes, int n_in,
                              void* d_out, int out_size, void* d_ws, size_t ws_size,
                              hipStream_t stream) {
    const float* x     = (const float*)d_in[0];
    const float* w_off = (const float*)d_in[1];
    const float* b_off = (const float*)d_in[2];
    const float* w_reg = (const float*)d_in[3];
    const float* b_reg = (const float*)d_in[4];
    float* out = (float*)d_out;
    float* ws  = (float*)d_ws;

    uint4* P      = (uint4*)(ws + P_OFF);
    float* offs   = ws + OFFS_OFF;
    unsigned short* wA_reg = (unsigned short*)(ws + WAREG_OFF);
    unsigned short* wA_off = (unsigned short*)(ws + WAOFF_OFF);

    prep_kernel<<<144, 256, 0, stream>>>(w_reg, w_off, wA_reg, wA_off);
    pad_kernel<<<(BB * 8 * PHW + 255) / 256, 256, 0, stream>>>(x, P);
    offset_conv_kernel<<<1024, 256, 0, stream>>>(P, wA_off, b_off, offs);
    deform_main_kernel<<<2048, 256, 0, stream>>>(P, offs, wA_reg, b_reg, out);
}

// Round 4
// 145.153 us; speedup vs baseline: 1.0791x; 1.0686x over previous
//
#include <hip/hip_runtime.h>
#include <math.h>

#define HH 128
#define WW 128
#define CC 64
#define BB 8
#define OC 64
#define OFFC 18
#define HW (HH*WW)
#define HP 136
#define WP 136
#define PHW (HP*WP)   /* 18496 */

typedef __attribute__((ext_vector_type(8))) _Float16 f16x8;
typedef __attribute__((ext_vector_type(4))) float f32x4;

// ws layout (floats):
//   P16:    8 img * 8 groups * PHW uint4 (8 fp16 ch each) = BB*32*PHW floats
//   offs:   (retained in layout, now unused)
//   wA_reg: 36864 fp16 (18432 fl) A-frag [(tap*2+kk)*64+o][quad][8j]
//   wA_off: 18432 fp16 (9216 fl)  [(tap*2+kk)*32+o][quad][8j], rows 18..31 zero
#define P_OFF      0
#define P_SIZE     (BB*32*PHW)
#define OFFS_OFF   (P_OFF + P_SIZE)
#define OFFS_SIZE  (BB*OFFC*HW)
#define WAREG_OFF  (OFFS_OFF + OFFS_SIZE)
#define WAREG_SIZE 18432
#define WAOFF_OFF  (WAREG_OFF + WAREG_SIZE)

#define PAD_BLOCKS 4624   /* BB*8*PHW / 256 */
#define PREP_BLOCKS 144

__device__ __forceinline__ unsigned short f2h(float f) {
    _Float16 t = (_Float16)f;
    unsigned short s;
    __builtin_memcpy(&s, &t, 2);
    return s;
}
__device__ __forceinline__ f16x8 u4_to_h8(uint4 u) {
    union { uint4 u; f16x8 h; } c; c.u = u; return c.h;
}
__device__ __forceinline__ uint4 h8_to_u4(f16x8 h) {
    union { uint4 u; f16x8 h; } c; c.h = h; return c.u;
}
__device__ __forceinline__ f16x8 splat8(float f) {
    _Float16 t = (_Float16)f;
    return (f16x8){t, t, t, t, t, t, t, t};
}

// merged prep (weight repack) + pad (fp16 zero-padded P) — one launch.
__global__ __launch_bounds__(256) void prep_pad_kernel(
    const float* __restrict__ x, uint4* __restrict__ P,
    const float* __restrict__ w_reg, const float* __restrict__ w_off,
    unsigned short* __restrict__ wA_reg, unsigned short* __restrict__ wA_off)
{
    int bid = blockIdx.x;
    int tid = threadIdx.x;
    if (bid < PAD_BLOCKS) {
        int idx = bid * 256 + tid;                // over BB*8*PHW
        int pos = idx % PHW;
        int ig  = idx / PHW;                      // img*8 + g
        int r   = pos / WP;
        int col = pos % WP;
        union { uint4 u; f16x8 h; } cv;
        cv.u = make_uint4(0u, 0u, 0u, 0u);
        if (r >= 4 && r <= 131 && col >= 4 && col <= 131) {
            const float* src = x + (ig * 8) * HW + (r - 4) * WW + (col - 4);
            #pragma unroll
            for (int e = 0; e < 8; ++e)
                cv.h[e] = (_Float16)src[e * HW];
        }
        P[idx] = cv.u;
    } else {
        int i = (bid - PAD_BLOCKS) * 256 + tid;
        if (i < 18 * 64 * 32) {
            int j = i & 7, quad = (i >> 3) & 3, o = (i >> 5) & 63, ks = i >> 11;
            int kt = ks >> 1, kk = ks & 1;
            int c = kk * 32 + quad * 8 + j;
            wA_reg[i] = f2h(w_reg[o * 576 + c * 9 + kt]);
        }
        if (i < 18 * 32 * 32) {
            int j = i & 7, quad = (i >> 3) & 3, o = (i >> 5) & 31, ks = i >> 10;
            int kt = ks >> 1, kk = ks & 1;
            int c = kk * 32 + quad * 8 + j;
            float v = (o < OFFC) ? w_off[(o * CC + c) * 9 + kt] : 0.0f;
            wA_off[i] = f2h(v);
        }
    }
}

struct Gather8 {
    uint4 a00, a01, a10, a11;   // group qp*2
    uint4 b00, b01, b10, b11;   // group qp*2+1
    float wx1, wy1;
};

__device__ __forceinline__ Gather8 issue_tap(
    const uint4* __restrict__ xq0, const uint4* __restrict__ xq1,
    int wv, int hv, int dx, int dy, float offx, float offy)
{
    const float scale = 129.0f / 127.0f;
    float pxf = ((float)wv + (float)dx) + offx;
    float pyf = ((float)hv + (float)dy) + offy;
    float qx = fminf(fmaxf(pxf * scale, -100.0f), 300.0f);
    float qy = fminf(fmaxf(pyf * scale, -100.0f), 300.0f);
    float x0f = floorf(qx), y0f = floorf(qy);
    Gather8 g;
    g.wx1 = qx - x0f;
    g.wy1 = qy - y0f;
    int ix0 = (int)x0f, iy0 = (int)y0f;
    int c0 = min(max(ix0 + 3, 0), WP - 2);
    int r0 = min(max(iy0 + 3, 0), HP - 1);
    int r1 = min(max(iy0 + 4, 0), HP - 1);
    int pr0 = r0 * WP + c0, pr1 = r1 * WP + c0;
    g.a00 = xq0[pr0]; g.a01 = xq0[pr0 + 1];
    g.a10 = xq0[pr1]; g.a11 = xq0[pr1 + 1];
    g.b00 = xq1[pr0]; g.b01 = xq1[pr0 + 1];
    g.b10 = xq1[pr1]; g.b11 = xq1[pr1 + 1];
    return g;
}

__device__ __forceinline__ void blend_write(
    uint4* __restrict__ dst, int qp, int pxl, const Gather8& g)
{
    f16x8 wx1v = splat8(g.wx1), wx0v = splat8(1.0f - g.wx1);
    f16x8 wy1v = splat8(g.wy1), wy0v = splat8(1.0f - g.wy1);
    f16x8 r0a = u4_to_h8(g.a00) * wx0v + u4_to_h8(g.a01) * wx1v;
    f16x8 r1a = u4_to_h8(g.a10) * wx0v + u4_to_h8(g.a11) * wx1v;
    dst[(qp * 2 + 0) * 64 + pxl] = h8_to_u4(r0a * wy0v + r1a * wy1v);
    f16x8 r0b = u4_to_h8(g.b00) * wx0v + u4_to_h8(g.b01) * wx1v;
    f16x8 r1b = u4_to_h8(g.b10) * wx0v + u4_to_h8(g.b11) * wx1v;
    dst[(qp * 2 + 1) * 64 + pxl] = h8_to_u4(r0b * wy0v + r1b * wy1v);
}

// Fused: per-block offset conv (3x66-col strip, 36 MFMA/wave) -> offs in LDS ->
// pipelined deform main loop (identical numerics to verified kernel; offsets
// now come from LDS instead of a global round-trip).
__global__ __launch_bounds__(256, 4) void fused_deform_kernel(
    const uint4* __restrict__ P, const unsigned short* __restrict__ wA_off,
    const float* __restrict__ b_off, const unsigned short* __restrict__ wA_reg,
    const float* __restrict__ b_reg, float* __restrict__ out)
{
    __shared__ uint4 shbuf[3 * 8 * 66];        // 25344 B: stage, then xs2 ping-pong
    __shared__ float offs_lds[OFFC * 64];      // 4608 B
    int img  = blockIdx.x & 7;
    int rest = blockIdx.x >> 3;                // 0..255
    int half = rest & 1;
    int pblk = rest >> 1;                      // row 0..127
    int tid  = threadIdx.x;
    int pxl  = tid & 63;                       // local px
    int qp   = tid >> 6;                       // group pair 0..3
    int lane = tid & 63;
    int wvid = tid >> 6;
    int wv = half * 64 + pxl;
    int hv = pblk;

    // ---- phase 1: stage 3 rows x 66 cols x 8 groups of P for the offset conv
    // output px wv needs P cols wv+dx+3 (dx 0..2) -> base col half*64 + 3
    for (int i = tid; i < 3 * 8 * 66; i += 256) {
        int r   = i / 528;
        int rem = i - r * 528;
        int g   = rem / 66;
        int j   = rem - g * 66;
        shbuf[(r * 8 + g) * 66 + j] =
            P[(img * 8 + g) * PHW + (pblk + 3 + r) * WP + (half * 64 + 3 + j)];
    }
    __syncthreads();

    // ---- phase 2: offset conv for this block's 64 px, 18 out-ch, via MFMA
    {
        int s2  = wvid & 1;                    // o-strip
        int ph2 = wvid >> 1;                   // 32-px half
        const f16x8* wOv = (const f16x8*)wA_off;
        const f16x8* xsc = (const f16x8*)shbuf;
        f32x4 oacc[2];
        oacc[0] = (f32x4){0.f, 0.f, 0.f, 0.f};
        oacc[1] = (f32x4){0.f, 0.f, 0.f, 0.f};
        for (int tap = 0; tap < 9; ++tap) {
            int dy = tap / 3, dx = tap % 3;
            f16x8 a0 = wOv[((tap * 2 + 0) * 32 + s2 * 16 + (lane & 15)) * 4 + (lane >> 4)];
            f16x8 a1 = wOv[((tap * 2 + 1) * 32 + s2 * 16 + (lane & 15)) * 4 + (lane >> 4)];
            #pragma unroll
            for (int pt = 0; pt < 2; ++pt) {
                int sj = ph2 * 32 + pt * 16 + (lane & 15) + dx;
                f16x8 b0 = xsc[(dy * 8 + (lane >> 4)) * 66 + sj];
                oacc[pt] = __builtin_amdgcn_mfma_f32_16x16x32_f16(a0, b0, oacc[pt], 0, 0, 0);
                f16x8 b1 = xsc[(dy * 8 + 4 + (lane >> 4)) * 66 + sj];
                oacc[pt] = __builtin_amdgcn_mfma_f32_16x16x32_f16(a1, b1, oacc[pt], 0, 0, 0);
            }
        }
        #pragma unroll
        for (int r = 0; r < 4; ++r) {
            int o = s2 * 16 + (lane >> 4) * 4 + r;
            if (o < OFFC) {
                float bias = b_off[o];
                #pragma unroll
                for (int pt = 0; pt < 2; ++pt) {
                    int p = ph2 * 32 + pt * 16 + (lane & 15);
                    offs_lds[o * 64 + p] = oacc[pt][r] + bias;
                }
            }
        }
    }
    __syncthreads();   // offs_lds ready; staged strip dead -> shbuf reusable as xs2

    // ---- phase 3: pipelined deform main loop
    const f16x8* wAv = (const f16x8*)wA_reg;
    const uint4* xq0 = P + (img * 8 + qp * 2 + 0) * PHW;
    const uint4* xq1 = P + (img * 8 + qp * 2 + 1) * PHW;
    int aidx = (wvid * 16 + (lane & 15)) * 4 + (lane >> 4);

    f32x4 acc[4];
    #pragma unroll
    for (int pt = 0; pt < 4; ++pt) acc[pt] = (f32x4){0.f, 0.f, 0.f, 0.f};

    float ox = offs_lds[0 * 64 + pxl], oy = offs_lds[1 * 64 + pxl];
    Gather8 cur = issue_tap(xq0, xq1, wv, hv, -1, -1, ox, oy);
    f16x8 a0c = wAv[0 * 256 + aidx];
    f16x8 a1c = wAv[1 * 256 + aidx];

    #pragma unroll
    for (int tap = 0; tap < 9; ++tap) {
        // 1. blend current corners (vmcnt wait auto-inserted at use), write LDS
        uint4* dst = shbuf + (tap & 1) * 512;
        blend_write(dst, qp, pxl, cur);

        // 2. issue next tap's gathers + A-frags (stay in flight across barrier)
        Gather8 nxt;
        f16x8 a0n, a1n;
        if (tap < 8) {
            int dx1 = (tap + 1) % 3 - 1, dy1 = (tap + 1) / 3 - 1;
            float oxn = offs_lds[(2 * tap + 2) * 64 + pxl];
            float oyn = offs_lds[(2 * tap + 3) * 64 + pxl];
            nxt = issue_tap(xq0, xq1, wv, hv, dx1, dy1, oxn, oyn);
            a0n = wAv[((tap + 1) * 2 + 0) * 256 + aidx];
            a1n = wAv[((tap + 1) * 2 + 1) * 256 + aidx];
        }

        // 3. barrier: drain LDS ops only — in-flight global loads survive
        asm volatile("s_waitcnt lgkmcnt(0)" ::: "memory");
        __builtin_amdgcn_s_barrier();
        asm volatile("" ::: "memory");

        // 4. consume this tap's LDS tile: 16 MFMAs
        const f16x8* xsv = (const f16x8*)(shbuf + (tap & 1) * 512);
        #pragma unroll
        for (int pt = 0; pt < 4; ++pt) {
            int pxi = pt * 16 + (lane & 15);
            f16x8 b0 = xsv[(lane >> 4) * 64 + pxi];
            acc[pt] = __builtin_amdgcn_mfma_f32_16x16x32_f16(a0c, b0, acc[pt], 0, 0, 0);
            f16x8 b1 = xsv[(4 + (lane >> 4)) * 64 + pxi];
            acc[pt] = __builtin_amdgcn_mfma_f32_16x16x32_f16(a1c, b1, acc[pt], 0, 0, 0);
        }

        // 5. rotate pipeline registers (SSA — fully unrolled)
        if (tap < 8) {
            cur = nxt; a0c = a0n; a1c = a1n;
        }
    }

    float* op = out + img * (OC * HW) + hv * WW + half * 64;
    #pragma unroll
    for (int r = 0; r < 4; ++r) {
        int o = wvid * 16 + (lane >> 4) * 4 + r;
        float bias = b_reg[o];
        #pragma unroll
        for (int pt = 0; pt < 4; ++pt)
            op[o * HW + pt * 16 + (lane & 15)] = acc[pt][r] + bias;
    }
}

extern "C" void kernel_launch(void* const* d_in, const int* in_sizes, int n_in,
                              void* d_out, int out_size, void* d_ws, size_t ws_size,
                              hipStream_t stream) {
    const float* x     = (const float*)d_in[0];
    const float* w_off = (const float*)d_in[1];
    const float* b_off = (const float*)d_in[2];
    const float* w_reg = (const float*)d_in[3];
    const float* b_reg = (const float*)d_in[4];
    float* out = (float*)d_out;
    float* ws  = (float*)d_ws;

    uint4* P      = (uint4*)(ws + P_OFF);
    unsigned short* wA_reg = (unsigned short*)(ws + WAREG_OFF);
    unsigned short* wA_off = (unsigned short*)(ws + WAOFF_OFF);

    prep_pad_kernel<<<PAD_BLOCKS + PREP_BLOCKS, 256, 0, stream>>>(
        x, P, w_reg, w_off, wA_reg, wA_off);
    fused_deform_kernel<<<2048, 256, 0, stream>>>(
        P, wA_off, b_off, wA_reg, b_reg, out);
}